// Round 1
// baseline (699.196 us; speedup 1.0000x reference)
//
#include <hip/hip_runtime.h>

#define B_ 8
#define T_ 14
#define HH 64
#define WW 64
#define CC 64
#define IMG (HH*WW*CC)  // 262144 elems per (b,t) image

typedef __attribute__((ext_vector_type(8))) short short8;
typedef __attribute__((ext_vector_type(4))) float floatx4;

// ws layout (bytes):
//   [0, 589824)        Wt: bf16 weights in MFMA B-fragment-major order
//   [1 MB, 9 MB)       c state fp32 [8][64][64][64]
//   [9 MB, 13 MB)      h ping bf16 [8][64][64][64]   (XOR-swizzled rows)
//   [13 MB, 17 MB)     h pong bf16                    (XOR-swizzled rows)
//   [17 MB, ~73 MB)    xbf: bf16 copy of x, XOR-swizzled rows
#define WT_OFF   0
#define C_OFF    (1u << 20)
#define H0_OFF   (C_OFF + 8u * 1024 * 1024)
#define H1_OFF   (H0_OFF + 4u * 1024 * 1024)
#define XBF_OFF  (H1_OFF + 4u * 1024 * 1024)

__device__ __forceinline__ unsigned short bf16_of(float f) {
    unsigned int x = __float_as_uint(f);
    unsigned int r = (x + 0x7FFFu + ((x >> 16) & 1u)) >> 16;  // RTNE
    return (unsigned short)r;
}
__device__ __forceinline__ unsigned int pack2(float a, float b) {
    return (unsigned int)bf16_of(a) | ((unsigned int)bf16_of(b) << 16);
}
__device__ __forceinline__ float hsig(float z) {
    return fminf(fmaxf(fmaf(z, 0.2f, 0.5f), 0.0f), 1.0f);
}
__device__ __forceinline__ float tanh_fast(float v) {
    float e = __expf(2.0f * v);
    return 1.0f - 2.0f / (e + 1.0f);
}

// direct global->LDS DMA, 16B per lane; lds dest must be wave-uniform base
__device__ __forceinline__ void dma16(const unsigned short* g, unsigned short* l) {
    __builtin_amdgcn_global_load_lds(
        (const __attribute__((address_space(1))) unsigned int*)g,
        (__attribute__((address_space(3))) unsigned int*)l, 16, 0, 0);
}

// Repack Wx,Wh [3,3,64,256] fp32 -> bf16 B-fragment-major:
// chunk fc = ((src*9+tap)*2+g)*16 + ntile ; element [lane][j] (j=0..7 contiguous)
// value = W[tap*64 + (g*32 + (lane>>4)*8 + j)]*256 + ntile*16 + (lane&15)
__global__ void repack_weights(const float* __restrict__ Wx,
                               const float* __restrict__ Wh,
                               unsigned short* __restrict__ Wt) {
    int u = blockIdx.x * 256 + threadIdx.x;    // 36864 threads
    int l  = u & 63;
    int nt = (u >> 6) & 15;
    int g  = (u >> 10) & 1;
    int st = u >> 11;                          // src*9 + tap, 0..17
    const float* W = (st < 9) ? Wx : Wh;
    int tap = (st < 9) ? st : st - 9;
    int n  = nt * 16 + (l & 15);
    int c0 = g * 32 + (l >> 4) * 8;
    unsigned short tmp[8];
    #pragma unroll
    for (int j = 0; j < 8; ++j) {
        tmp[j] = bf16_of(W[(tap * 64 + c0 + j) * 256 + n]);
    }
    *(uint4*)(Wt + (size_t)u * 8) = *(const uint4*)tmp;
}

// Pre-convert x fp32 -> bf16, storing each 4096-elem row region XOR-swizzled:
// dest elem d (within row): px = d>>6, u = d&63 holds source channel
// u ^ (((px+1)&7)<<3)  (the "+1" because A-tile column = px+1 due to halo).
__global__ void convert_x(const float* __restrict__ x,
                          unsigned short* __restrict__ xbf) {
    size_t P0 = ((size_t)blockIdx.x * 256 + threadIdx.x) * 8;   // 29360128 elems total
    int d  = (int)(P0 & 4095);
    int px = d >> 6;
    int u0 = d & 63;                                             // multiple of 8
    int mask = ((px + 1) & 7) << 3;
    const float* src = x + (P0 & ~(size_t)4095) + (size_t)(px * 64 + (u0 ^ mask));
    float4 f0 = *(const float4*)src;
    float4 f1 = *(const float4*)(src + 4);
    uint4 o;
    o.x = pack2(f0.x, f0.y); o.y = pack2(f0.z, f0.w);
    o.z = pack2(f1.x, f1.y); o.w = pack2(f1.z, f1.w);
    *(uint4*)(xbf + P0) = o;
}

// LDS A-tile: bf16 [src 2][ky 3][col 66][ch 64]; col 0 and 65 are zero halo.
// Element addresses are XOR-swizzled: logical (col, ch) lives at
// (col, ch ^ ((col&7)<<3)).  Sources (xbf, h) are pre-swizzled so the linear
// global_load_lds lands data in swizzled position (rule: both-sides-or-neither).
#define AT(s, r, col, c) ((((s) * 3 + (r)) * 66 + (col)) * 64 + (c))

// One ConvLSTM timestep as implicit GEMM.
// Block = one image row (b,y): M=64 pixels, N=256 gate-channels, K=18 taps x 64.
// 4 waves; wave w owns CHANNELS [16w,16w+16) of every gate (nt indexes the gate),
// so the epilogue has all 4 gates per (pixel,channel) in registers - no z transpose.
template<bool FIRST>
__global__ __launch_bounds__(256, 2) void lstm_step_mfma(
    const float* __restrict__ x,              // [8,14,64,64,64] fp32 (residual)
    const unsigned short* __restrict__ xbf,   // bf16 swizzled copy of x
    const unsigned short* __restrict__ Wt,    // repacked bf16 weights
    const float* __restrict__ bias,           // [256] fp32
    float* __restrict__ out,                  // [8,14,64,64,64] fp32 (y = h + x)
    float* __restrict__ cst,                  // [8,64,64,64] fp32
    const unsigned short* __restrict__ hprev, // [8,64,64,64] bf16 swizzled
    unsigned short* __restrict__ hnext,       // [8,64,64,64] bf16 swizzled
    int t)
{
    __shared__ __align__(16) unsigned short aT[2 * 3 * 66 * 64];   // 50688 B

    const int tid = threadIdx.x;
    const int l   = tid & 63;
    const int w   = tid >> 6;          // wave id == channel-group id
    const int y   = blockIdx.x & 63;
    const int b   = blockIdx.x >> 6;
    const int m16 = l & 15;
    const int q   = l >> 4;
    const int ch  = w * 16 + m16;      // this lane's output channel

    // ---- stage x rows + h rows straight into LDS via DMA ----
    {
        const size_t xrowbase = ((size_t)(b * T_ + t) * HH) << 12;   // elems
        #pragma unroll
        for (int r = 0; r < 3; ++r) {
            int iy = y + r - 1;
            unsigned short* dst = aT + AT(0, r, 1, 0);
            if ((unsigned)iy < (unsigned)HH) {
                const unsigned short* src = xbf + xrowbase + ((size_t)iy << 12);
                dma16(src + tid * 8,        dst + (w << 9));
                dma16(src + tid * 8 + 2048, dst + (w << 9) + 2048);
            } else {
                uint4 z = {0, 0, 0, 0};
                *(uint4*)(dst + tid * 8) = z;
                *(uint4*)(dst + tid * 8 + 2048) = z;
            }
        }
        if (!FIRST) {
            #pragma unroll
            for (int r = 0; r < 3; ++r) {
                int iy = y + r - 1;
                unsigned short* dst = aT + AT(1, r, 1, 0);
                if ((unsigned)iy < (unsigned)HH) {
                    const unsigned short* src = hprev + (((size_t)(b * HH + iy)) << 12);
                    dma16(src + tid * 8,        dst + (w << 9));
                    dma16(src + tid * 8 + 2048, dst + (w << 9) + 2048);
                } else {
                    uint4 z = {0, 0, 0, 0};
                    *(uint4*)(dst + tid * 8) = z;
                    *(uint4*)(dst + tid * 8 + 2048) = z;
                }
            }
        }
        // ---- zero halo columns 0 and 65 (full 128B col blocks: swizzle-proof) ----
        if (tid < 96) {
            int grp = tid >> 3, l8 = tid & 7;
            int src = grp / 6, rem = grp % 6;
            int r = rem >> 1, colh = (rem & 1) * 65;
            uint4 z = {0, 0, 0, 0};
            *(uint4*)(aT + AT(src, r, colh, l8 * 8)) = z;
        }
    }
    __syncthreads();   // drains vmcnt -> DMA complete

    // ---- accumulators init with bias (bias depends only on column n) ----
    floatx4 acc[4][4];
    #pragma unroll
    for (int nt = 0; nt < 4; ++nt) {
        float bv = bias[nt * 64 + ch];
        #pragma unroll
        for (int mt = 0; mt < 4; ++mt) {
            acc[mt][nt][0] = bv; acc[mt][nt][1] = bv;
            acc[mt][nt][2] = bv; acc[mt][nt][3] = bv;
        }
    }

    // ---- K loop: 9 taps x {x,h} x 2 k-chunks of 32 ----
    const int NSRC = FIRST ? 1 : 2;
    #pragma unroll
    for (int ky = 0; ky < 3; ++ky) {
        #pragma unroll
        for (int kx = 0; kx < 3; ++kx) {
            // swizzle mask: col = mt*16 + m16 + kx, and mt*16 % 8 == 0
            const int swz = ((m16 + kx) & 7) << 3;
            #pragma unroll
            for (int src = 0; src < NSRC; ++src) {
                #pragma unroll
                for (int g = 0; g < 2; ++g) {
                    const int lo = (g * 32 + q * 8) ^ swz;
                    short8 af[4];
                    #pragma unroll
                    for (int mt = 0; mt < 4; ++mt) {
                        int col = mt * 16 + m16 + kx;   // 0..65 (halo handles kx-1)
                        af[mt] = *(const short8*)(aT + AT(src, ky, col, lo));
                    }
                    short8 bf[4];
                    int fcb = ((src * 9 + ky * 3 + kx) * 2 + g) * 16;
                    #pragma unroll
                    for (int nt = 0; nt < 4; ++nt) {
                        bf[nt] = *(const short8*)(Wt + (size_t)(fcb + nt * 4 + w) * 512 + l * 8);
                    }
                    #pragma unroll
                    for (int mt = 0; mt < 4; ++mt) {
                        #pragma unroll
                        for (int nt = 0; nt < 4; ++nt) {
                            acc[mt][nt] = __builtin_amdgcn_mfma_f32_16x16x32_bf16(
                                af[mt], bf[nt], acc[mt][nt], 0, 0, 0);
                        }
                    }
                }
            }
        }
    }

    // ---- gates, cell update, h, fused residual: all in registers ----
    // acc[mt][gate][r] is z_gate at pixel m = mt*16 + q*4 + r, channel ch.
    const size_t rbase = ((size_t)(b * HH + y)) << 12;          // c/h row base
    float* crow = cst + rbase;
    unsigned short* hrow = hnext + rbase;
    const float* xr  = x   + (((size_t)(b * T_ + t) * HH + y) << 12);
    float* orow      = out + (((size_t)(b * T_ + t) * HH + y) << 12);
    #pragma unroll
    for (int mt = 0; mt < 4; ++mt) {
        #pragma unroll
        for (int r = 0; r < 4; ++r) {
            int m   = mt * 16 + q * 4 + r;
            int idx = m * 64 + ch;
            float zi = acc[mt][0][r], zf = acc[mt][1][r];
            float zg = acc[mt][2][r], zo = acc[mt][3][r];
            float ig = hsig(zi), fg = hsig(zf), og = hsig(zo);
            float gg = tanh_fast(zg);
            float cn;
            if (FIRST) cn = ig * gg;
            else       cn = fmaf(fg, crow[idx], ig * gg);
            float hv = og * tanh_fast(cn);
            crow[idx] = cn;
            // h stored XOR-swizzled so next step's DMA staging lands it right
            hrow[m * 64 + (ch ^ (((m + 1) & 7) << 3))] = bf16_of(hv);
            orow[idx] = hv + xr[idx];
        }
    }
}

extern "C" void kernel_launch(void* const* d_in, const int* in_sizes, int n_in,
                              void* d_out, int out_size, void* d_ws, size_t ws_size,
                              hipStream_t stream) {
    const float* x    = (const float*)d_in[0];
    const float* Wx   = (const float*)d_in[1];
    const float* Wh   = (const float*)d_in[2];
    const float* bias = (const float*)d_in[3];
    float* out = (float*)d_out;

    unsigned short* Wt  = (unsigned short*)((char*)d_ws + WT_OFF);
    float* cst          = (float*)((char*)d_ws + C_OFF);
    unsigned short* h0  = (unsigned short*)((char*)d_ws + H0_OFF);
    unsigned short* h1  = (unsigned short*)((char*)d_ws + H1_OFF);
    unsigned short* xbf = (unsigned short*)((char*)d_ws + XBF_OFF);

    repack_weights<<<144, 256, 0, stream>>>(Wx, Wh, Wt);
    convert_x<<<14336, 256, 0, stream>>>(x, xbf);   // 29360128 elems / 8 / 256

    const int grid = B_ * HH;  // 512 blocks: one image row each
    lstm_step_mfma<true><<<grid, 256, 0, stream>>>(x, xbf, Wt, bias, out, cst, h0, h0, 0);
    for (int t = 1; t < T_; ++t) {
        unsigned short* hp = (t & 1) ? h0 : h1;   // written by step t-1
        unsigned short* hn = (t & 1) ? h1 : h0;
        lstm_step_mfma<false><<<grid, 256, 0, stream>>>(x, xbf, Wt, bias, out, cst, hp, hn, t);
    }
}

// Round 2
// 538.772 us; speedup vs baseline: 1.2978x; 1.2978x over previous
//
#include <hip/hip_runtime.h>

#define B_ 8
#define T_ 14
#define HH 64
#define WW 64
#define CC 64
#define FF 64
#define IMG (HH*WW*CC)  // 262144 elems per (b,t) image

typedef __attribute__((ext_vector_type(8))) short short8;
typedef __attribute__((ext_vector_type(4))) float floatx4;

// ws layout (bytes):
//   [0, 589824)                 Wt: bf16 weights in MFMA B-fragment-major order
//   [1 MB, 9 MB)                c state fp32 [8][64][64][64]
//   [9 MB, 13 MB)               h ping bf16 [8][64][64][64]  (linear)
//   [13 MB, 17 MB)              h pong bf16                   (linear)
#define WT_OFF   0
#define C_OFF    (1u << 20)
#define H0_OFF   (C_OFF + 8u * 1024 * 1024)
#define H1_OFF   (H0_OFF + 4u * 1024 * 1024)

__device__ __forceinline__ unsigned short bf16_of(float f) {
    unsigned int x = __float_as_uint(f);
    unsigned int r = (x + 0x7FFFu + ((x >> 16) & 1u)) >> 16;  // RTNE
    return (unsigned short)r;
}
__device__ __forceinline__ unsigned int pack2(float a, float b) {
    return (unsigned int)bf16_of(a) | ((unsigned int)bf16_of(b) << 16);
}
__device__ __forceinline__ float hsig(float z) {
    return fminf(fmaxf(fmaf(z, 0.2f, 0.5f), 0.0f), 1.0f);
}
__device__ __forceinline__ float tanh_fast(float v) {
    float e = __expf(2.0f * v);
    return 1.0f - 2.0f / (e + 1.0f);
}

// Repack Wx,Wh [3,3,64,256] fp32 -> bf16 B-fragment-major:
// chunk fc = ((src*9+tap)*2+g)*16 + ntile ; element [lane][j] (j=0..7 contiguous)
// value = W[tap*64 + (g*32 + (lane>>4)*8 + j)]*256 + ntile*16 + (lane&15)
__global__ void repack_weights(const float* __restrict__ Wx,
                               const float* __restrict__ Wh,
                               unsigned short* __restrict__ Wt) {
    int u = blockIdx.x * 256 + threadIdx.x;    // 36864 threads
    int l  = u & 63;
    int nt = (u >> 6) & 15;
    int g  = (u >> 10) & 1;
    int st = u >> 11;                          // src*9 + tap, 0..17
    const float* W = (st < 9) ? Wx : Wh;
    int tap = (st < 9) ? st : st - 9;
    int n  = nt * 16 + (l & 15);
    int c0 = g * 32 + (l >> 4) * 8;
    unsigned short tmp[8];
    #pragma unroll
    for (int j = 0; j < 8; ++j) {
        tmp[j] = bf16_of(W[(tap * 64 + c0 + j) * 256 + n]);
    }
    *(uint4*)(Wt + (size_t)u * 8) = *(const uint4*)tmp;
}

// LDS A-tile: bf16 [src 2][ky 3][col 66][ch 64]; col 0 and 65 are zero halo.
// XOR-swizzled: logical (col, c) lives at element (col, c ^ ((col&7)<<3)).
// Spreads the K-loop's ds_read_b128 (16 lanes at same ch-range, cols 128B
// apart -> one 4-bank group unswizzled) across 8 bank groups: balanced.
// Both staging writes and K-loop reads apply the same XOR (both-sides rule).
#define AT(s, r, col, c) ((((s) * 3 + (r)) * 66 + (col)) * 64 + (c))

// One ConvLSTM timestep as implicit GEMM.
// Block = one image row (b,y): M=64 pixels, N=256 gate-channels, K=18 taps x 64.
// 4 waves; wave w owns gate w (n in [64w, 64w+64)).
template<bool FIRST>
__global__ __launch_bounds__(256, 2) void lstm_step_mfma(
    const float* __restrict__ x,          // [8,14,64,64,64] fp32
    const unsigned short* __restrict__ Wt,// repacked bf16 weights
    const float* __restrict__ bias,       // [256] fp32
    float* __restrict__ out,              // [8,14,64,64,64] fp32 (y = h + x)
    float* __restrict__ cst,              // [8,64,64,64] fp32
    const unsigned short* __restrict__ hprev, // [8,64,64,64] bf16
    unsigned short* __restrict__ hnext,       // [8,64,64,64] bf16
    int t)
{
    __shared__ __align__(16) float smem[64 * 260];   // 66560 B; aliased as A-tile
    unsigned short* aT = (unsigned short*)smem;

    const int tid = threadIdx.x;
    const int l   = tid & 63;
    const int w   = tid >> 6;          // wave id == gate id
    const int y   = blockIdx.x & 63;
    const int b   = blockIdx.x >> 6;
    const int m16 = l & 15;
    const int q   = l >> 4;

    const float* xbase = x + (size_t)(b * T_ + t) * IMG;

    // ---- stage x rows (fp32 -> bf16), 16 elems/thread/row, swizzled writes ----
    {
        const int col = (tid >> 2) + 1;
        const int ch  = (tid & 3) * 16;
        const int sm  = (col & 7) << 3;            // swizzle mask for this col
        #pragma unroll
        for (int r = 0; r < 3; ++r) {
            int iy = y + r - 1;
            uint4 u0 = {0, 0, 0, 0}, u1 = {0, 0, 0, 0};
            if ((unsigned)iy < (unsigned)HH) {
                const float4* s4 = (const float4*)(xbase + iy * (WW * CC)) + tid * 4;
                float4 f0 = s4[0], f1 = s4[1], f2 = s4[2], f3 = s4[3];
                u0.x = pack2(f0.x, f0.y); u0.y = pack2(f0.z, f0.w);
                u0.z = pack2(f1.x, f1.y); u0.w = pack2(f1.z, f1.w);
                u1.x = pack2(f2.x, f2.y); u1.y = pack2(f2.z, f2.w);
                u1.z = pack2(f3.x, f3.y); u1.w = pack2(f3.z, f3.w);
            }
            *(uint4*)(aT + AT(0, r, col, ch ^ sm))       = u0;
            *(uint4*)(aT + AT(0, r, col, (ch + 8) ^ sm)) = u1;
        }
        // ---- stage h rows (bf16 copy), or zeros on first step ----
        #pragma unroll
        for (int r = 0; r < 3; ++r) {
            int iy = y + r - 1;
            uint4 u0 = {0, 0, 0, 0}, u1 = {0, 0, 0, 0};
            if (!FIRST && (unsigned)iy < (unsigned)HH) {
                const uint4* hp = (const uint4*)(hprev + (size_t)(b * HH + iy) * (WW * CC));
                u0 = hp[tid * 2];
                u1 = hp[tid * 2 + 1];
            }
            *(uint4*)(aT + AT(1, r, col, ch ^ sm))       = u0;
            *(uint4*)(aT + AT(1, r, col, (ch + 8) ^ sm)) = u1;
        }
        // ---- zero halo columns 0 and 65 (swizzled addresses, zero data) ----
        if (tid < 96) {
            int grp = tid >> 3, l8 = tid & 7;
            int src = grp / 6, rem = grp % 6;
            int r = rem >> 1, colh = (rem & 1) * 65;
            int hm = (colh & 7) << 3;
            uint4 z = {0, 0, 0, 0};
            *(uint4*)(aT + AT(src, r, colh, (l8 * 8) ^ hm)) = z;
        }
    }
    __syncthreads();

    // ---- accumulators init with bias (bias depends only on column n) ----
    floatx4 acc[4][4];
    #pragma unroll
    for (int nt = 0; nt < 4; ++nt) {
        float bv = bias[w * 64 + nt * 16 + m16];
        #pragma unroll
        for (int mt = 0; mt < 4; ++mt) {
            acc[mt][nt][0] = bv; acc[mt][nt][1] = bv;
            acc[mt][nt][2] = bv; acc[mt][nt][3] = bv;
        }
    }

    // ---- K loop: 9 taps x {x,h} x 2 k-chunks of 32 ----
    const int NSRC = FIRST ? 1 : 2;
    #pragma unroll
    for (int ky = 0; ky < 3; ++ky) {
        #pragma unroll
        for (int kx = 0; kx < 3; ++kx) {
            // col = mt*16 + m16 + kx and mt*16 % 8 == 0, so (col&7) = (m16+kx)&7
            const int swz = ((m16 + kx) & 7) << 3;
            #pragma unroll
            for (int src = 0; src < NSRC; ++src) {
                #pragma unroll
                for (int g = 0; g < 2; ++g) {
                    const int lo = (g * 32 + q * 8) ^ swz;
                    short8 af[4];
                    #pragma unroll
                    for (int mt = 0; mt < 4; ++mt) {
                        int col = mt * 16 + m16 + kx;   // 0..65 (halo handles kx-1)
                        af[mt] = *(const short8*)(aT + AT(src, ky, col, lo));
                    }
                    short8 bf[4];
                    int fc = (((src * 9 + ky * 3 + kx) * 2 + g) * 16 + w * 4);
                    #pragma unroll
                    for (int nt = 0; nt < 4; ++nt) {
                        bf[nt] = *(const short8*)(Wt + (size_t)(fc + nt) * 512 + l * 8);
                    }
                    #pragma unroll
                    for (int mt = 0; mt < 4; ++mt) {
                        #pragma unroll
                        for (int nt = 0; nt < 4; ++nt) {
                            acc[mt][nt] = __builtin_amdgcn_mfma_f32_16x16x32_bf16(
                                af[mt], bf[nt], acc[mt][nt], 0, 0, 0);
                        }
                    }
                }
            }
        }
    }

    // ---- transpose z through LDS: zT[64 m][260 pad] fp32 ----
    __syncthreads();   // all waves done reading aT
    #pragma unroll
    for (int mt = 0; mt < 4; ++mt) {
        #pragma unroll
        for (int nt = 0; nt < 4; ++nt) {
            int n = w * 64 + nt * 16 + m16;
            #pragma unroll
            for (int r = 0; r < 4; ++r) {
                int m = mt * 16 + q * 4 + r;
                smem[m * 260 + n] = acc[mt][nt][r];
            }
        }
    }
    __syncthreads();

    // ---- gates, cell update, h, fused residual ----
    const int fch   = (tid & 15) * 4;
    const int mbase = tid >> 4;
    const float* xres = xbase + y * (WW * CC);
    float* outrow = out + (size_t)(b * T_ + t) * IMG + y * (WW * CC);
    #pragma unroll
    for (int i = 0; i < 4; ++i) {
        int m = mbase + i * 16;
        const float* zr = smem + m * 260;
        float4 zi = *(const float4*)(zr + fch);
        float4 zf = *(const float4*)(zr + 64 + fch);
        float4 zg = *(const float4*)(zr + 128 + fch);
        float4 zo = *(const float4*)(zr + 192 + fch);
        size_t sidx = (size_t)(b * HH + y) * (WW * CC) + m * 64 + fch;
        float4 cold = {0, 0, 0, 0};
        if (!FIRST) cold = *(const float4*)(cst + sidx);
        float4 xv = *(const float4*)(xres + m * 64 + fch);

        float cn[4], hv[4];
        float zia[4] = {zi.x, zi.y, zi.z, zi.w};
        float zfa[4] = {zf.x, zf.y, zf.z, zf.w};
        float zga[4] = {zg.x, zg.y, zg.z, zg.w};
        float zoa[4] = {zo.x, zo.y, zo.z, zo.w};
        float ca[4]  = {cold.x, cold.y, cold.z, cold.w};
        float xa[4]  = {xv.x, xv.y, xv.z, xv.w};
        #pragma unroll
        for (int k = 0; k < 4; ++k) {
            float ig = hsig(zia[k]);
            float fg = hsig(zfa[k]);
            float gg = tanh_fast(zga[k]);
            float og = hsig(zoa[k]);
            cn[k] = FIRST ? (ig * gg) : fmaf(fg, ca[k], ig * gg);
            hv[k] = og * tanh_fast(cn[k]);
        }
        float4 cnew = {cn[0], cn[1], cn[2], cn[3]};
        *(float4*)(cst + sidx) = cnew;
        ushort4 hb;
        hb.x = bf16_of(hv[0]); hb.y = bf16_of(hv[1]);
        hb.z = bf16_of(hv[2]); hb.w = bf16_of(hv[3]);
        *(ushort4*)(hnext + sidx) = hb;
        float4 yo = {hv[0] + xa[0], hv[1] + xa[1], hv[2] + xa[2], hv[3] + xa[3]};
        *(float4*)(outrow + m * 64 + fch) = yo;
    }
}

extern "C" void kernel_launch(void* const* d_in, const int* in_sizes, int n_in,
                              void* d_out, int out_size, void* d_ws, size_t ws_size,
                              hipStream_t stream) {
    const float* x    = (const float*)d_in[0];
    const float* Wx   = (const float*)d_in[1];
    const float* Wh   = (const float*)d_in[2];
    const float* bias = (const float*)d_in[3];
    float* out = (float*)d_out;

    unsigned short* Wt = (unsigned short*)((char*)d_ws + WT_OFF);
    float* cst         = (float*)((char*)d_ws + C_OFF);
    unsigned short* h0 = (unsigned short*)((char*)d_ws + H0_OFF);
    unsigned short* h1 = (unsigned short*)((char*)d_ws + H1_OFF);

    repack_weights<<<144, 256, 0, stream>>>(Wx, Wh, Wt);

    const int grid = B_ * HH;  // 512 blocks: one image row each
    lstm_step_mfma<true><<<grid, 256, 0, stream>>>(x, Wt, bias, out, cst, h0, h0, 0);
    for (int t = 1; t < T_; ++t) {
        unsigned short* hp = (t & 1) ? h0 : h1;   // written by step t-1
        unsigned short* hn = (t & 1) ? h1 : h0;
        lstm_step_mfma<false><<<grid, 256, 0, stream>>>(x, Wt, bias, out, cst, hp, hn, t);
    }
}